// Round 20
// baseline (408.005 us; speedup 1.0000x reference)
//
#include <hip/hip_runtime.h>
#include <hip/hip_bf16.h>

#define N_NODES 20000
#define N_EDGES 320000
#define DIM 128
#define HEADS 3
#define LAYERS 3
#define NGRAPH 64
#define NEG_SLOPE 0.2f
#define NODE_BLOCKS ((N_NODES + 63) / 64)   // 313

typedef const __hip_bfloat16* bfp;
typedef __hip_bfloat16 bf16;
typedef short v8s __attribute__((ext_vector_type(8)));
typedef float v4f __attribute__((ext_vector_type(4)));

#define GLD_LDS(gp, lp) \
    __builtin_amdgcn_global_load_lds( \
        (const __attribute__((address_space(1))) void*)(gp), \
        (__attribute__((address_space(3))) void*)(lp), 16, 0, 0)

__device__ __forceinline__ float b2f(unsigned short u) {
    return __uint_as_float(((unsigned)u) << 16);
}
__device__ __forceinline__ float lo2f(unsigned u) { return __uint_as_float(u << 16); }
__device__ __forceinline__ float hi2f(unsigned u) { return __uint_as_float(u & 0xffff0000u); }
__device__ __forceinline__ float leaky(float z) {
    return z >= 0.f ? z : NEG_SLOPE * z;
}
__device__ __forceinline__ unsigned packbf(float a, float b) {
    bf16 x = __float2bfloat16(a), y = __float2bfloat16(b);
    return (unsigned)*(unsigned short*)&x | ((unsigned)*(unsigned short*)&y << 16);
}
__device__ __forceinline__ unsigned short f2bfbits(float v) {
    bf16 x = __float2bfloat16(v);
    return *(unsigned short*)&x;
}

// XOR-swizzled 32-col chunk staging (validated R13)
__device__ __forceinline__ void stage_swz(const short* base, int t0, int K,
                                          int k0, short* lds, int gidx) {
    int row = gidx >> 2, pos = gidx & 3;
    int kch = pos ^ ((row >> 1) & 3);
    GLD_LDS(base + (size_t)(t0 + row) * K + k0 + kch * 8, lds + gidx * 8);
}
__device__ __forceinline__ v8s fragx(const short* lds, int R, int q) {
    int g = R * 4 + (q ^ ((R >> 1) & 3));
    return *(const v8s*)(lds + g * 8);
}

// Full-panel staging: A 64x128 = 1024 granules; B 128x128 = 2048 granules.
__device__ __forceinline__ void stage_panelA(const short* base, int t0, int K,
                                             int k0, short* lds, int tid) {
#pragma unroll
    for (int j = 0; j < 4; ++j) {
        int g = j * 256 + tid;
        stage_swz(base, t0, K, k0 + (g >> 8) * 32, lds + (g >> 8) * 2048, g & 255);
    }
}
__device__ __forceinline__ void stage_panelB(const short* base, int t0, int K,
                                             int k0, short* lds, int tid) {
#pragma unroll
    for (int j = 0; j < 8; ++j) {
        int g = j * 256 + tid;
        stage_swz(base, t0, K, k0 + (g >> 9) * 32, lds + (g >> 9) * 4096, g & 511);
    }
}

// ---------------- init: zero workspace region + dtype detect ----------------
__global__ void init_kernel(unsigned* __restrict__ z, int nzd,
                            const unsigned short* __restrict__ probe,
                            int* __restrict__ dflag) {
    int gid = blockIdx.x * 256 + threadIdx.x;
    for (int i = gid; i < nzd; i += gridDim.x * 256) z[i] = 0u;
    if (blockIdx.x == 0) {
        int c = 0;
#pragma unroll
        for (int j = 0; j < 64; ++j) {
            unsigned short u = probe[threadIdx.x * 64 + j];
            c += (((u >> 7) & 0xFF) >= 140) ? 1 : 0;
        }
        for (int o = 32; o > 0; o >>= 1) c += __shfl_down(c, o);
        __shared__ int r[4];
        if ((threadIdx.x & 63) == 0) r[threadIdx.x >> 6] = c;
        __syncthreads();
        if (threadIdx.x == 0) *dflag = r[0] + r[1] + r[2] + r[3];
    }
}

// ---------------- fused cvt (all float inputs -> bf16) + edge histogram -----
#define NCVT 9
struct CvtArgs {
    const void* src[NCVT];
    bf16* dst[NCVT];
    int n4[NCVT];
    int n[NCVT];
};
__global__ void cvtcount_kernel(CvtArgs args, const int* __restrict__ flag,
                                const int* __restrict__ dst, int* __restrict__ deg,
                                int cvtBlocks) {
    if ((int)blockIdx.x >= cvtBlocks) {
        int e = (blockIdx.x - cvtBlocks) * 256 + threadIdx.x;
        if (e < N_EDGES) atomicAdd(&deg[dst[e]], 1);
        return;
    }
    int i = blockIdx.x * 256 + threadIdx.x;
    int f = (*flag) > 8;
#pragma unroll
    for (int s = 0; s < NCVT; ++s) {
        int ns4 = args.n4[s];
        if (i < ns4) {
            int ns = args.n[s];
            int base = i * 4;
            bf16* dstp = args.dst[s];
            if (f) {
                const float* sp = (const float*)args.src[s];
                if (base + 3 < ns) {
                    float4 v = *(const float4*)(sp + base);
                    ushort4 pk = { f2bfbits(v.x), f2bfbits(v.y),
                                   f2bfbits(v.z), f2bfbits(v.w) };
                    *(ushort4*)(dstp + base) = pk;
                } else {
                    for (int j = 0; j < 4 && base + j < ns; ++j)
                        dstp[base + j] = __float2bfloat16(sp[base + j]);
                }
            } else {
                const bf16* sp = (const bf16*)args.src[s];
                if (base + 3 < ns) {
                    *(ushort4*)(dstp + base) = *(const ushort4*)(sp + base);
                } else {
                    for (int j = 0; j < 4 && base + j < ns; ++j)
                        dstp[base + j] = sp[base + j];
                }
            }
            return;
        }
        i -= ns4;
    }
}

// ---------------- fused: deg scan (shfl block-scan) + gptr binary search ----
__global__ void scan_gptr_kernel(const int* __restrict__ cnt, int* __restrict__ ptr,
                                 const int* __restrict__ gid, int* __restrict__ gptr) {
    int tid = threadIdx.x;
    if (tid <= NGRAPH) {
        int lo = 0, hi = N_NODES;
        while (lo < hi) {
            int mid = (lo + hi) >> 1;
            if (gid[mid] < tid) lo = mid + 1; else hi = mid;
        }
        gptr[tid] = lo;
    }
    const int chunk = (N_NODES + 255) / 256;
    int b = tid * chunk, e = min(b + chunk, N_NODES);
    int loc = 0;
    for (int i = b; i < e; ++i) loc += cnt[i];
    int lane = tid & 63, wv = tid >> 6;
    int v = loc;
#pragma unroll
    for (int o = 1; o < 64; o <<= 1) {
        int t = __shfl_up(v, o);
        if (lane >= o) v += t;
    }
    __shared__ int wsum[4];
    if (lane == 63) wsum[wv] = v;
    __syncthreads();
    int wo = 0;
    for (int j = 0; j < wv; ++j) wo += wsum[j];
    int run = wo + v - loc;
    if (tid == 255) ptr[N_NODES] = wsum[0] + wsum[1] + wsum[2] + wsum[3];
    for (int i = b; i < e; ++i) { ptr[i] = run; run += cnt[i]; }
}

__global__ void sentinel_kernel(bf16* out, int n) {
    int i = blockIdx.x * 256 + threadIdx.x;
    if (i < n) out[i] = __float2bfloat16(2.0f);
}

// ---------------- MFMA GEMM, full-panel staged, BM=64 -----------------------
template <int MODE, int KSUP>
__global__ __launch_bounds__(256) void gemm_mfma(
    const bf16* __restrict__ A, const bf16* __restrict__ B,
    bf16* __restrict__ C, int M, int N,
    const bf16* __restrict__ bias, const bf16* __restrict__ resid,
    int do_relu, const bf16* __restrict__ p2w, float* __restrict__ gpart)
{
    __shared__ short lsA[8192];
    __shared__ short lsB[16384];
    const int tid  = threadIdx.x;
    const int wave = tid >> 6;
    const int lane = tid & 63;
    const int quad = lane >> 4;
    const int r16  = lane & 15;
    const int m0 = blockIdx.x * 64;
    const int n0 = blockIdx.y * 128;
    const int K = KSUP * 128;
    const short* As = (const short*)A;
    const short* Bs = (const short*)B;

    v4f acc[8];
#pragma unroll
    for (int t = 0; t < 8; ++t) acc[t] = (v4f){0.f, 0.f, 0.f, 0.f};

#pragma unroll
    for (int ks = 0; ks < KSUP; ++ks) {
        const int k0 = ks * 128;
        stage_panelA(As, m0, K, k0, lsA, tid);
        stage_panelB(Bs, n0, K, k0, lsB, tid);
        __syncthreads();
#pragma unroll
        for (int c = 0; c < 4; ++c) {
            v8s a = fragx(lsA + c * 2048, wave * 16 + r16, quad);
#pragma unroll
            for (int t = 0; t < 8; ++t) {
                v8s b = fragx(lsB + c * 4096, t * 16 + r16, quad);
                acc[t] = __builtin_amdgcn_mfma_f32_16x16x32_bf16(a, b, acc[t], 0, 0, 0);
            }
        }
        if (ks + 1 < KSUP) __syncthreads();
    }

    const int mb = m0 + wave * 16;

    if (MODE == 2) {
        float pwv[8], bbv[8];
#pragma unroll
        for (int t = 0; t < 8; ++t) {
            int n = n0 + t * 16 + r16;
            pwv[t] = __bfloat162float(p2w[n]);
            bbv[t] = __bfloat162float(bias[n]);
        }
#pragma unroll
        for (int reg = 0; reg < 4; ++reg) {
            float g = 0.f;
#pragma unroll
            for (int t = 0; t < 8; ++t)
                g += fmaxf(acc[t][reg] + bbv[t], 0.f) * pwv[t];
#pragma unroll
            for (int o = 1; o < 16; o <<= 1) g += __shfl_xor(g, o);
            int m = mb + quad * 4 + reg;
            if (r16 == 0 && m < M) gpart[(size_t)blockIdx.y * N_NODES + m] = g;
        }
        return;
    }

#pragma unroll
    for (int t = 0; t < 8; ++t) {
        const int n = n0 + t * 16 + r16;
        float bb = bias ? __bfloat162float(bias[n]) : 0.f;
#pragma unroll
        for (int reg = 0; reg < 4; ++reg) {
            const int m = mb + quad * 4 + reg;
            if (m >= M) continue;
            float v = acc[t][reg];
            if (bias) {
                v += bb;
                if (do_relu) v = fmaxf(v, 0.f);
            }
            if (resid) v += __bfloat162float(resid[(size_t)m * N + n]);
            C[(size_t)m * N + n] = __float2bfloat16(v);
        }
    }
}

// ---------------- fc body (plain row-major C + fused scores), K=128 ---------
__device__ __forceinline__ void fc_block(
    const short* As, const short* Bs, bf16* __restrict__ C, int M,
    const bf16* __restrict__ ans, const bf16* __restrict__ and_,
    float* __restrict__ s_ns, float* __restrict__ s_nd,
    short* lsA, short* lsB, int tid, int mbx, int head)
{
    const int wave = tid >> 6;
    const int lane = tid & 63;
    const int quad = lane >> 4;
    const int r16  = lane & 15;
    const int m0 = mbx * 64;
    const int n0 = head * 128;
    const int N = HEADS * DIM, K = DIM;

    v4f acc[8];
#pragma unroll
    for (int t = 0; t < 8; ++t) acc[t] = (v4f){0.f, 0.f, 0.f, 0.f};

    stage_panelA(As, m0, K, 0, lsA, tid);
    stage_panelB(Bs, n0, K, 0, lsB, tid);
    __syncthreads();
#pragma unroll
    for (int c = 0; c < 4; ++c) {
        v8s a = fragx(lsA + c * 2048, wave * 16 + r16, quad);
#pragma unroll
        for (int t = 0; t < 8; ++t) {
            v8s b = fragx(lsB + c * 4096, t * 16 + r16, quad);
            acc[t] = __builtin_amdgcn_mfma_f32_16x16x32_bf16(a, b, acc[t], 0, 0, 0);
        }
    }

    const int mb = m0 + wave * 16;
#pragma unroll
    for (int t = 0; t < 8; ++t) {
        const int n = n0 + t * 16 + r16;
#pragma unroll
        for (int reg = 0; reg < 4; ++reg) {
            const int m = mb + quad * 4 + reg;
            if (m >= M) continue;
            C[(size_t)m * N + n] = __float2bfloat16(acc[t][reg]);
        }
    }
    float ansv[8], andv[8];
#pragma unroll
    for (int t = 0; t < 8; ++t) {
        int dcol = t * 16 + r16;
        ansv[t] = __bfloat162float(ans[head * 128 + dcol]);
        andv[t] = __bfloat162float(and_[head * 128 + dcol]);
    }
#pragma unroll
    for (int reg = 0; reg < 4; ++reg) {
        float pns = 0.f, pnd = 0.f;
#pragma unroll
        for (int t = 0; t < 8; ++t) {
            pns += acc[t][reg] * ansv[t];
            pnd += acc[t][reg] * andv[t];
        }
#pragma unroll
        for (int o = 1; o < 16; o <<= 1) {
            pns += __shfl_xor(pns, o);
            pnd += __shfl_xor(pnd, o);
        }
        int m = mb + quad * 4 + reg;
        if (r16 == 0 && m < M) {
            s_ns[m * 3 + head] = pns;
            s_nd[m * 3 + head] = pnd;
        }
    }
}

// ---------------- merged: pool(d-1) | fill(d==0) | fc(d) --------------------
__global__ __launch_bounds__(256) void poolfc_kernel(
    const bf16* __restrict__ pfeat, const float* __restrict__ gp,
    const int* __restrict__ gptr, float* __restrict__ out_acc,
    const bf16* __restrict__ A, const bf16* __restrict__ B,
    bf16* __restrict__ C, int M,
    const bf16* __restrict__ ans, const bf16* __restrict__ and_,
    float* __restrict__ s_ns, float* __restrict__ s_nd,
    const int* __restrict__ src, const int* __restrict__ dst,
    const int* __restrict__ rp, int* __restrict__ cursor,
    int* __restrict__ esrc,
    int poolBlocks, int fillBlocks)
{
    __shared__ short lsA[8192];
    __shared__ short lsB[16384];
    __shared__ float red[4];
    const int tid = threadIdx.x;
    if ((int)blockIdx.x < poolBlocks) {
        const int g = blockIdx.x >> 3;
        const int chunk = blockIdx.x & 7;
        const int beg = gptr[g], end = gptr[g + 1];
        if (beg >= end) return;
        float m = -1e30f;
        for (int i = beg + tid; i < end; i += 256)
            m = fmaxf(m, gp[i] + gp[N_NODES + i]);
#pragma unroll
        for (int o = 32; o > 0; o >>= 1) m = fmaxf(m, __shfl_xor(m, o));
        if ((tid & 63) == 0) red[tid >> 6] = m;
        __syncthreads();
        m = fmaxf(fmaxf(red[0], red[1]), fmaxf(red[2], red[3]));
        __syncthreads();
        float s = 0.f;
        for (int i = beg + tid; i < end; i += 256)
            s += __expf(gp[i] + gp[N_NODES + i] - m);
#pragma unroll
        for (int o = 32; o > 0; o >>= 1) s += __shfl_xor(s, o);
        if ((tid & 63) == 0) red[tid >> 6] = s;
        __syncthreads();
        float inv = 1.f / (red[0] + red[1] + red[2] + red[3]);
        const int p = tid >> 7;
        const int c = tid & 127;
        float acc = 0.f;
        for (int i = beg + chunk * 2 + p; i < end; i += 16) {
            float w = __expf(gp[i] + gp[N_NODES + i] - m);
            acc += w * __bfloat162float(pfeat[(size_t)i * DIM + c]);
        }
        acc *= inv;
        atomicAdd(&out_acc[g * DIM + c], acc);
        return;
    }
    if ((int)blockIdx.x < poolBlocks + fillBlocks) {
        int e = (blockIdx.x - poolBlocks) * 256 + tid;
        if (e < N_EDGES) {
            int d = dst[e];
            int pos = rp[d] + atomicAdd(&cursor[d], 1);
            esrc[pos] = src[e];
        }
        return;
    }
    const int t = blockIdx.x - poolBlocks - fillBlocks;
    const int mbx = t % NODE_BLOCKS;
    const int head = t / NODE_BLOCKS;
    fc_block((const short*)A, (const short*)B, C, M, ans, and_, s_ns, s_nd,
             lsA, lsB, tid, mbx, head);
}

// ---------------- aggregate: one WAVE per dst node, two-phase ---------------
// Phase A: lane j computes edge j's (p0,p1,p2,src) lane-PARALLEL, one 16B
// LDS record per edge. Phase B: gather loop reads records via broadcast
// ds_read_b128 (static addresses -> deep MLP on the gathers). No barrier
// needed: per-wave slab + wave-lockstep ordering.
__global__ __launch_bounds__(256) void agg_kernel(
    const unsigned* __restrict__ h2, const int* __restrict__ rp,
    const int* __restrict__ esrc, const float* __restrict__ s_ns,
    const float* __restrict__ s_nd, bf16* __restrict__ agg)
{
    __shared__ float4 pv[4][64];
    const int wv = threadIdx.x >> 6;
    const int lane = threadIdx.x & 63;
    const int node = blockIdx.x * 4 + wv;
    if (node >= N_NODES) return;
    const int beg = rp[node], end = rp[node + 1];
    const int cnt = end - beg;
    unsigned* outp = (unsigned*)(agg + (size_t)node * (HEADS * DIM));
    if (cnt <= 0) {
        outp[lane] = 0u; outp[64 + lane] = 0u; outp[128 + lane] = 0u;
        return;
    }
    const float snd0 = s_nd[node * 3 + 0];
    const float snd1 = s_nd[node * 3 + 1];
    const float snd2 = s_nd[node * 3 + 2];
    float ss0 = 0.f, ss1 = 0.f, ss2 = 0.f;
    float a0 = 0.f, a1 = 0.f, a2 = 0.f, a3 = 0.f, a4 = 0.f, a5 = 0.f;
    for (int c0 = 0; c0 < cnt; c0 += 64) {
        const int ce = min(64, cnt - c0);
        if (lane < ce) {
            int s = esrc[beg + c0 + lane];
            float4 r;
            r.x = __expf(leaky(s_ns[s * 3 + 0] + snd0));
            r.y = __expf(leaky(s_ns[s * 3 + 1] + snd1));
            r.z = __expf(leaky(s_ns[s * 3 + 2] + snd2));
            r.w = __int_as_float(s);
            pv[wv][lane] = r;
        }
#pragma unroll 8
        for (int j = 0; j < ce; ++j) {
            float4 e = pv[wv][j];              // broadcast ds_read_b128
            int s = __float_as_int(e.w);
            ss0 += e.x; ss1 += e.y; ss2 += e.z;
            const unsigned* hp = h2 + (size_t)s * 192;
            unsigned w0 = hp[lane];
            unsigned w1 = hp[64 + lane];
            unsigned w2 = hp[128 + lane];
            a0 += e.x * lo2f(w0); a1 += e.x * hi2f(w0);
            a2 += e.y * lo2f(w1); a3 += e.y * hi2f(w1);
            a4 += e.z * lo2f(w2); a5 += e.z * hi2f(w2);
        }
    }
    float i0 = 1.f / ss0, i1 = 1.f / ss1, i2 = 1.f / ss2;
    outp[lane]       = packbf(a0 * i0, a1 * i0);
    outp[64 + lane]  = packbf(a2 * i1, a3 * i1);
    outp[128 + lane] = packbf(a4 * i2, a5 * i2);
}

// ---------------- final pool + fused last-block writeout --------------------
__global__ __launch_bounds__(256) void pool_acc(
    const bf16* __restrict__ feat, const float* __restrict__ gp,
    const int* __restrict__ gptr, float* __restrict__ out_acc,
    int* __restrict__ wcount, void* __restrict__ out,
    const int* __restrict__ dflag)
{
    const int g = blockIdx.x;
    const int chunk = blockIdx.y;
    const int tid = threadIdx.x;
    const int beg = gptr[g], end = gptr[g + 1];
    __shared__ float red[4];
    if (beg < end) {
        float m = -1e30f;
        for (int i = beg + tid; i < end; i += 256)
            m = fmaxf(m, gp[i] + gp[N_NODES + i]);
#pragma unroll
        for (int o = 32; o > 0; o >>= 1) m = fmaxf(m, __shfl_xor(m, o));
        if ((tid & 63) == 0) red[tid >> 6] = m;
        __syncthreads();
        m = fmaxf(fmaxf(red[0], red[1]), fmaxf(red[2], red[3]));
        __syncthreads();
        float s = 0.f;
        for (int i = beg + tid; i < end; i += 256)
            s += __expf(gp[i] + gp[N_NODES + i] - m);
#pragma unroll
        for (int o = 32; o > 0; o >>= 1) s += __shfl_xor(s, o);
        if ((tid & 63) == 0) red[tid >> 6] = s;
        __syncthreads();
        float inv = 1.f / (red[0] + red[1] + red[2] + red[3]);
        const int p = tid >> 7;
        const int c = tid & 127;
        float acc = 0.f;
        for (int i = beg + chunk * 2 + p; i < end; i += 16) {
            float w = __expf(gp[i] + gp[N_NODES + i] - m);
            acc += w * __bfloat162float(feat[(size_t)i * DIM + c]);
        }
        acc *= inv;
        atomicAdd(&out_acc[g * DIM + c], acc);
    }
    // last-block-out writeout (all blocks arrive, incl. empty-graph blocks)
    __threadfence();
    __shared__ int lastFlag;
    if (tid == 0) {
        int prev = atomicAdd(wcount, 1);
        lastFlag = (prev == NGRAPH * 8 - 1) ? 1 : 0;
    }
    __syncthreads();
    if (lastFlag) {
        int f = (*dflag) > 8;
        for (int i = tid; i < NGRAPH * DIM; i += 256) {
            float v = __hip_atomic_load(&out_acc[i], __ATOMIC_RELAXED,
                                        __HIP_MEMORY_SCOPE_AGENT) * (1.f / 3.f);
            if (f) ((float*)out)[i] = v;
            else ((bf16*)out)[i] = __float2bfloat16(v);
        }
    }
}

// ---------------- host launcher ----------------
extern "C" void kernel_launch(void* const* d_in, const int* in_sizes, int n_in,
                              void* d_out, int out_size, void* d_ws, size_t ws_size,
                              hipStream_t stream)
{
    const void* feat_in = d_in[0];
    const int* src = (const int*)d_in[1];
    const int* dst = (const int*)d_in[2];
    const int* gid = (const int*)d_in[3];

    char* base = (char*)d_ws;
    size_t off = 0;
    auto carve = [&](size_t bytes) -> void* {
        void* p = base + off;
        off = (off + bytes + 255) & ~(size_t)255;
        return p;
    };
    int* dflag = (int*)carve(256);   // NOT zeroed; init block 0 stores it
    // zeroed region: deg | cursor | out_acc | wcount
    size_t zbytes = sizeof(int) * 2 * N_NODES + sizeof(float) * NGRAPH * DIM + 256;
    char* zreg  = (char*)carve(zbytes);
    int* deg    = (int*)zreg;
    int* cursor = deg + N_NODES;
    float* out_acc = (float*)(cursor + N_NODES);
    int* wcount = (int*)(out_acc + NGRAPH * DIM);
    float* gpart3 = (float*)carve(sizeof(float) * LAYERS * 2 * N_NODES);
    int* rp     = (int*)carve(sizeof(int) * (N_NODES + 1));
    int* gptr   = (int*)carve(sizeof(int) * (NGRAPH + 1));
    int* esrc   = (int*)carve(sizeof(int) * N_EDGES);
    float* s_ns = (float*)carve(sizeof(float) * N_NODES * HEADS);
    float* s_nd = (float*)carve(sizeof(float) * N_NODES * HEADS);
    bf16* featA = (bf16*)carve(sizeof(bf16) * N_NODES * DIM);
    bf16* featB = (bf16*)carve(sizeof(bf16) * N_NODES * DIM);
    bf16* cfc   = (bf16*)carve(sizeof(bf16) * LAYERS * HEADS * DIM * DIM);
    bf16* cans  = (bf16*)carve(sizeof(bf16) * LAYERS * HEADS * DIM);
    bf16* cand  = (bf16*)carve(sizeof(bf16) * LAYERS * HEADS * DIM);
    bf16* ctw   = (bf16*)carve(sizeof(bf16) * LAYERS * DIM * HEADS * DIM);
    bf16* ctb   = (bf16*)carve(sizeof(bf16) * LAYERS * DIM);
    bf16* cp1w  = (bf16*)carve(sizeof(bf16) * LAYERS * 2 * DIM * DIM);
    bf16* cp1b  = (bf16*)carve(sizeof(bf16) * LAYERS * 2 * DIM);
    bf16* cp2w  = (bf16*)carve(sizeof(bf16) * LAYERS * 2 * DIM);
    bf16* hbuf   = (bf16*)carve(sizeof(bf16) * N_NODES * HEADS * DIM);
    bf16* aggbuf = (bf16*)carve(sizeof(bf16) * N_NODES * HEADS * DIM);
    carve(131072);   // pad: GEMM A-tile tail overreads

    if (off > ws_size) {
        sentinel_kernel<<<(out_size + 255) / 256, 256, 0, stream>>>(
            (bf16*)d_out, out_size);
        return;
    }

    init_kernel<<<128, 256, 0, stream>>>(
        (unsigned*)zreg, (int)(zbytes / 4), (const unsigned short*)feat_in, dflag);

    CvtArgs ca;
    const int cvt_n[NCVT] = {
        N_NODES * DIM, LAYERS * HEADS * DIM * DIM, LAYERS * HEADS * DIM,
        LAYERS * HEADS * DIM, LAYERS * DIM * HEADS * DIM, LAYERS * DIM,
        LAYERS * 2 * DIM * DIM, LAYERS * 2 * DIM, LAYERS * 2 * DIM };
    bf16* cvt_dst[NCVT] = { featA, cfc, cans, cand, ctw, ctb, cp1w, cp1b, cp2w };
    const int cvt_src_idx[NCVT] = { 0, 4, 5, 6, 7, 8, 9, 10, 11 };
    int total4 = 0;
    for (int s = 0; s < NCVT; ++s) {
        ca.src[s] = d_in[cvt_src_idx[s]];
        ca.dst[s] = cvt_dst[s];
        ca.n[s] = cvt_n[s];
        ca.n4[s] = (cvt_n[s] + 3) / 4;
        total4 += ca.n4[s];
    }
    const int cvtBlocks = (total4 + 255) / 256;
    const int cntBlocks = (N_EDGES + 255) / 256;
    cvtcount_kernel<<<cvtBlocks + cntBlocks, 256, 0, stream>>>(
        ca, dflag, dst, deg, cvtBlocks);

    scan_gptr_kernel<<<1, 256, 0, stream>>>(deg, rp, gid, gptr);

    bf16* fin = featA;
    bf16* fout = featB;
    for (int d = 0; d < LAYERS; ++d) {
        float* gpart = gpart3 + (size_t)d * 2 * N_NODES;
        const int poolBlocks = (d == 0) ? 0 : NGRAPH * 8;
        const int fillBlocks = (d == 0) ? cntBlocks : 0;
        poolfc_kernel<<<poolBlocks + fillBlocks + NODE_BLOCKS * 3, 256, 0, stream>>>(
            fin, (d == 0) ? nullptr : gpart3 + (size_t)(d - 1) * 2 * N_NODES,
            gptr, out_acc,
            fin, cfc + (size_t)d * HEADS * DIM * DIM, hbuf, N_NODES,
            cans + (size_t)d * HEADS * DIM, cand + (size_t)d * HEADS * DIM,
            s_ns, s_nd, src, dst, rp, cursor, esrc, poolBlocks, fillBlocks);
        agg_kernel<<<(N_NODES + 3) / 4, 256, 0, stream>>>(
            (const unsigned*)hbuf, rp, esrc, s_ns, s_nd, aggbuf);
        gemm_mfma<0, 3><<<dim3(NODE_BLOCKS, 1), 256, 0, stream>>>(
            aggbuf, ctw + (size_t)d * DIM * HEADS * DIM, fout,
            N_NODES, DIM, ctb + (size_t)d * DIM, fin,
            (d < LAYERS - 1) ? 1 : 0, nullptr, nullptr);
        gemm_mfma<2, 1><<<dim3(NODE_BLOCKS, 2), 256, 0, stream>>>(
            fout, cp1w + (size_t)d * 2 * DIM * DIM, nullptr,
            N_NODES, 2 * DIM, cp1b + (size_t)d * 2 * DIM, nullptr, 1,
            cp2w + (size_t)d * 2 * DIM, gpart);
        bf16* t = fin; fin = fout; fout = t;
    }
    pool_acc<<<dim3(NGRAPH, 8), 256, 0, stream>>>(
        fin, gpart3 + (size_t)2 * 2 * N_NODES, gptr, out_acc,
        wcount, d_out, dflag);
}

// Round 21
// 369.792 us; speedup vs baseline: 1.1033x; 1.1033x over previous
//
#include <hip/hip_runtime.h>
#include <hip/hip_bf16.h>

#define N_NODES 20000
#define N_EDGES 320000
#define DIM 128
#define HEADS 3
#define LAYERS 3
#define NGRAPH 64
#define NEG_SLOPE 0.2f
#define NODE_BLOCKS ((N_NODES + 63) / 64)   // 313

typedef const __hip_bfloat16* bfp;
typedef __hip_bfloat16 bf16;
typedef short v8s __attribute__((ext_vector_type(8)));
typedef float v4f __attribute__((ext_vector_type(4)));

#define GLD_LDS(gp, lp) \
    __builtin_amdgcn_global_load_lds( \
        (const __attribute__((address_space(1))) void*)(gp), \
        (__attribute__((address_space(3))) void*)(lp), 16, 0, 0)

__device__ __forceinline__ float b2f(unsigned short u) {
    return __uint_as_float(((unsigned)u) << 16);
}
__device__ __forceinline__ float lo2f(unsigned u) { return __uint_as_float(u << 16); }
__device__ __forceinline__ float hi2f(unsigned u) { return __uint_as_float(u & 0xffff0000u); }
__device__ __forceinline__ float leaky(float z) {
    return z >= 0.f ? z : NEG_SLOPE * z;
}
__device__ __forceinline__ unsigned packbf(float a, float b) {
    bf16 x = __float2bfloat16(a), y = __float2bfloat16(b);
    return (unsigned)*(unsigned short*)&x | ((unsigned)*(unsigned short*)&y << 16);
}
__device__ __forceinline__ unsigned short f2bfbits(float v) {
    bf16 x = __float2bfloat16(v);
    return *(unsigned short*)&x;
}

// XOR-swizzled 32-col chunk staging (validated R13)
__device__ __forceinline__ void stage_swz(const short* base, int t0, int K,
                                          int k0, short* lds, int gidx) {
    int row = gidx >> 2, pos = gidx & 3;
    int kch = pos ^ ((row >> 1) & 3);
    GLD_LDS(base + (size_t)(t0 + row) * K + k0 + kch * 8, lds + gidx * 8);
}
__device__ __forceinline__ v8s fragx(const short* lds, int R, int q) {
    int g = R * 4 + (q ^ ((R >> 1) & 3));
    return *(const v8s*)(lds + g * 8);
}

// Full-panel staging: A 64x128 = 1024 granules; B 128x128 = 2048 granules.
__device__ __forceinline__ void stage_panelA(const short* base, int t0, int K,
                                             int k0, short* lds, int tid) {
#pragma unroll
    for (int j = 0; j < 4; ++j) {
        int g = j * 256 + tid;
        stage_swz(base, t0, K, k0 + (g >> 8) * 32, lds + (g >> 8) * 2048, g & 255);
    }
}
__device__ __forceinline__ void stage_panelB(const short* base, int t0, int K,
                                             int k0, short* lds, int tid) {
#pragma unroll
    for (int j = 0; j < 8; ++j) {
        int g = j * 256 + tid;
        stage_swz(base, t0, K, k0 + (g >> 9) * 32, lds + (g >> 9) * 4096, g & 511);
    }
}

// ---------------- init: zero workspace region + dtype detect ----------------
__global__ void init_kernel(unsigned* __restrict__ z, int nzd,
                            const unsigned short* __restrict__ probe,
                            int* __restrict__ dflag) {
    int gid = blockIdx.x * 256 + threadIdx.x;
    for (int i = gid; i < nzd; i += gridDim.x * 256) z[i] = 0u;
    if (blockIdx.x == 0) {
        int c = 0;
#pragma unroll
        for (int j = 0; j < 64; ++j) {
            unsigned short u = probe[threadIdx.x * 64 + j];
            c += (((u >> 7) & 0xFF) >= 140) ? 1 : 0;
        }
        for (int o = 32; o > 0; o >>= 1) c += __shfl_down(c, o);
        __shared__ int r[4];
        if ((threadIdx.x & 63) == 0) r[threadIdx.x >> 6] = c;
        __syncthreads();
        if (threadIdx.x == 0) *dflag = r[0] + r[1] + r[2] + r[3];
    }
}

// ---------------- fused cvt (all float inputs -> bf16) + edge histogram -----
#define NCVT 9
struct CvtArgs {
    const void* src[NCVT];
    bf16* dst[NCVT];
    int n4[NCVT];
    int n[NCVT];
};
__global__ void cvtcount_kernel(CvtArgs args, const int* __restrict__ flag,
                                const int* __restrict__ dst, int* __restrict__ deg,
                                int cvtBlocks) {
    if ((int)blockIdx.x >= cvtBlocks) {
        int e = (blockIdx.x - cvtBlocks) * 256 + threadIdx.x;
        if (e < N_EDGES) atomicAdd(&deg[dst[e]], 1);
        return;
    }
    int i = blockIdx.x * 256 + threadIdx.x;
    int f = (*flag) > 8;
#pragma unroll
    for (int s = 0; s < NCVT; ++s) {
        int ns4 = args.n4[s];
        if (i < ns4) {
            int ns = args.n[s];
            int base = i * 4;
            bf16* dstp = args.dst[s];
            if (f) {
                const float* sp = (const float*)args.src[s];
                if (base + 3 < ns) {
                    float4 v = *(const float4*)(sp + base);
                    ushort4 pk = { f2bfbits(v.x), f2bfbits(v.y),
                                   f2bfbits(v.z), f2bfbits(v.w) };
                    *(ushort4*)(dstp + base) = pk;
                } else {
                    for (int j = 0; j < 4 && base + j < ns; ++j)
                        dstp[base + j] = __float2bfloat16(sp[base + j]);
                }
            } else {
                const bf16* sp = (const bf16*)args.src[s];
                if (base + 3 < ns) {
                    *(ushort4*)(dstp + base) = *(const ushort4*)(sp + base);
                } else {
                    for (int j = 0; j < 4 && base + j < ns; ++j)
                        dstp[base + j] = sp[base + j];
                }
            }
            return;
        }
        i -= ns4;
    }
}

// ---------------- fused: deg scan (shfl block-scan) + gptr binary search ----
__global__ void scan_gptr_kernel(const int* __restrict__ cnt, int* __restrict__ ptr,
                                 const int* __restrict__ gid, int* __restrict__ gptr) {
    int tid = threadIdx.x;
    if (tid <= NGRAPH) {
        int lo = 0, hi = N_NODES;
        while (lo < hi) {
            int mid = (lo + hi) >> 1;
            if (gid[mid] < tid) lo = mid + 1; else hi = mid;
        }
        gptr[tid] = lo;
    }
    const int chunk = (N_NODES + 255) / 256;
    int b = tid * chunk, e = min(b + chunk, N_NODES);
    int loc = 0;
    for (int i = b; i < e; ++i) loc += cnt[i];
    int lane = tid & 63, wv = tid >> 6;
    int v = loc;
#pragma unroll
    for (int o = 1; o < 64; o <<= 1) {
        int t = __shfl_up(v, o);
        if (lane >= o) v += t;
    }
    __shared__ int wsum[4];
    if (lane == 63) wsum[wv] = v;
    __syncthreads();
    int wo = 0;
    for (int j = 0; j < wv; ++j) wo += wsum[j];
    int run = wo + v - loc;
    if (tid == 255) ptr[N_NODES] = wsum[0] + wsum[1] + wsum[2] + wsum[3];
    for (int i = b; i < e; ++i) { ptr[i] = run; run += cnt[i]; }
}

__global__ void sentinel_kernel(bf16* out, int n) {
    int i = blockIdx.x * 256 + threadIdx.x;
    if (i < n) out[i] = __float2bfloat16(2.0f);
}

// ---------------- MFMA GEMM, full-panel staged, BM=64 -----------------------
template <int MODE, int KSUP>
__global__ __launch_bounds__(256) void gemm_mfma(
    const bf16* __restrict__ A, const bf16* __restrict__ B,
    bf16* __restrict__ C, int M, int N,
    const bf16* __restrict__ bias, const bf16* __restrict__ resid,
    int do_relu, const bf16* __restrict__ p2w, float* __restrict__ gpart)
{
    __shared__ short lsA[8192];
    __shared__ short lsB[16384];
    const int tid  = threadIdx.x;
    const int wave = tid >> 6;
    const int lane = tid & 63;
    const int quad = lane >> 4;
    const int r16  = lane & 15;
    const int m0 = blockIdx.x * 64;
    const int n0 = blockIdx.y * 128;
    const int K = KSUP * 128;
    const short* As = (const short*)A;
    const short* Bs = (const short*)B;

    v4f acc[8];
#pragma unroll
    for (int t = 0; t < 8; ++t) acc[t] = (v4f){0.f, 0.f, 0.f, 0.f};

#pragma unroll
    for (int ks = 0; ks < KSUP; ++ks) {
        const int k0 = ks * 128;
        stage_panelA(As, m0, K, k0, lsA, tid);
        stage_panelB(Bs, n0, K, k0, lsB, tid);
        __syncthreads();
#pragma unroll
        for (int c = 0; c < 4; ++c) {
            v8s a = fragx(lsA + c * 2048, wave * 16 + r16, quad);
#pragma unroll
            for (int t = 0; t < 8; ++t) {
                v8s b = fragx(lsB + c * 4096, t * 16 + r16, quad);
                acc[t] = __builtin_amdgcn_mfma_f32_16x16x32_bf16(a, b, acc[t], 0, 0, 0);
            }
        }
        if (ks + 1 < KSUP) __syncthreads();
    }

    const int mb = m0 + wave * 16;

    if (MODE == 2) {
        float pwv[8], bbv[8];
#pragma unroll
        for (int t = 0; t < 8; ++t) {
            int n = n0 + t * 16 + r16;
            pwv[t] = __bfloat162float(p2w[n]);
            bbv[t] = __bfloat162float(bias[n]);
        }
#pragma unroll
        for (int reg = 0; reg < 4; ++reg) {
            float g = 0.f;
#pragma unroll
            for (int t = 0; t < 8; ++t)
                g += fmaxf(acc[t][reg] + bbv[t], 0.f) * pwv[t];
#pragma unroll
            for (int o = 1; o < 16; o <<= 1) g += __shfl_xor(g, o);
            int m = mb + quad * 4 + reg;
            if (r16 == 0 && m < M) gpart[(size_t)blockIdx.y * N_NODES + m] = g;
        }
        return;
    }

#pragma unroll
    for (int t = 0; t < 8; ++t) {
        const int n = n0 + t * 16 + r16;
        float bb = bias ? __bfloat162float(bias[n]) : 0.f;
#pragma unroll
        for (int reg = 0; reg < 4; ++reg) {
            const int m = mb + quad * 4 + reg;
            if (m >= M) continue;
            float v = acc[t][reg];
            if (bias) {
                v += bb;
                if (do_relu) v = fmaxf(v, 0.f);
            }
            if (resid) v += __bfloat162float(resid[(size_t)m * N + n]);
            C[(size_t)m * N + n] = __float2bfloat16(v);
        }
    }
}

// ---------------- fc body (plain row-major C + fused scores), K=128 ---------
__device__ __forceinline__ void fc_block(
    const short* As, const short* Bs, bf16* __restrict__ C, int M,
    const bf16* __restrict__ ans, const bf16* __restrict__ and_,
    float* __restrict__ s_ns, float* __restrict__ s_nd,
    short* lsA, short* lsB, int tid, int mbx, int head)
{
    const int wave = tid >> 6;
    const int lane = tid & 63;
    const int quad = lane >> 4;
    const int r16  = lane & 15;
    const int m0 = mbx * 64;
    const int n0 = head * 128;
    const int N = HEADS * DIM, K = DIM;

    v4f acc[8];
#pragma unroll
    for (int t = 0; t < 8; ++t) acc[t] = (v4f){0.f, 0.f, 0.f, 0.f};

    stage_panelA(As, m0, K, 0, lsA, tid);
    stage_panelB(Bs, n0, K, 0, lsB, tid);
    __syncthreads();
#pragma unroll
    for (int c = 0; c < 4; ++c) {
        v8s a = fragx(lsA + c * 2048, wave * 16 + r16, quad);
#pragma unroll
        for (int t = 0; t < 8; ++t) {
            v8s b = fragx(lsB + c * 4096, t * 16 + r16, quad);
            acc[t] = __builtin_amdgcn_mfma_f32_16x16x32_bf16(a, b, acc[t], 0, 0, 0);
        }
    }

    const int mb = m0 + wave * 16;
#pragma unroll
    for (int t = 0; t < 8; ++t) {
        const int n = n0 + t * 16 + r16;
#pragma unroll
        for (int reg = 0; reg < 4; ++reg) {
            const int m = mb + quad * 4 + reg;
            if (m >= M) continue;
            C[(size_t)m * N + n] = __float2bfloat16(acc[t][reg]);
        }
    }
    float ansv[8], andv[8];
#pragma unroll
    for (int t = 0; t < 8; ++t) {
        int dcol = t * 16 + r16;
        ansv[t] = __bfloat162float(ans[head * 128 + dcol]);
        andv[t] = __bfloat162float(and_[head * 128 + dcol]);
    }
#pragma unroll
    for (int reg = 0; reg < 4; ++reg) {
        float pns = 0.f, pnd = 0.f;
#pragma unroll
        for (int t = 0; t < 8; ++t) {
            pns += acc[t][reg] * ansv[t];
            pnd += acc[t][reg] * andv[t];
        }
#pragma unroll
        for (int o = 1; o < 16; o <<= 1) {
            pns += __shfl_xor(pns, o);
            pnd += __shfl_xor(pnd, o);
        }
        int m = mb + quad * 4 + reg;
        if (r16 == 0 && m < M) {
            s_ns[m * 3 + head] = pns;
            s_nd[m * 3 + head] = pnd;
        }
    }
}

// ---------------- merged: pool(d-1) | fill(d==0) | fc(d) --------------------
__global__ __launch_bounds__(256) void poolfc_kernel(
    const bf16* __restrict__ pfeat, const float* __restrict__ gp,
    const int* __restrict__ gptr, float* __restrict__ out_acc,
    const bf16* __restrict__ A, const bf16* __restrict__ B,
    bf16* __restrict__ C, int M,
    const bf16* __restrict__ ans, const bf16* __restrict__ and_,
    float* __restrict__ s_ns, float* __restrict__ s_nd,
    const int* __restrict__ src, const int* __restrict__ dst,
    const int* __restrict__ rp, int* __restrict__ cursor,
    int* __restrict__ esrc,
    int poolBlocks, int fillBlocks)
{
    __shared__ short lsA[8192];
    __shared__ short lsB[16384];
    __shared__ float red[4];
    const int tid = threadIdx.x;
    if ((int)blockIdx.x < poolBlocks) {
        const int g = blockIdx.x >> 3;
        const int chunk = blockIdx.x & 7;
        const int beg = gptr[g], end = gptr[g + 1];
        if (beg >= end) return;
        float m = -1e30f;
        for (int i = beg + tid; i < end; i += 256)
            m = fmaxf(m, gp[i] + gp[N_NODES + i]);
#pragma unroll
        for (int o = 32; o > 0; o >>= 1) m = fmaxf(m, __shfl_xor(m, o));
        if ((tid & 63) == 0) red[tid >> 6] = m;
        __syncthreads();
        m = fmaxf(fmaxf(red[0], red[1]), fmaxf(red[2], red[3]));
        __syncthreads();
        float s = 0.f;
        for (int i = beg + tid; i < end; i += 256)
            s += __expf(gp[i] + gp[N_NODES + i] - m);
#pragma unroll
        for (int o = 32; o > 0; o >>= 1) s += __shfl_xor(s, o);
        if ((tid & 63) == 0) red[tid >> 6] = s;
        __syncthreads();
        float inv = 1.f / (red[0] + red[1] + red[2] + red[3]);
        const int p = tid >> 7;
        const int c = tid & 127;
        float acc = 0.f;
        for (int i = beg + chunk * 2 + p; i < end; i += 16) {
            float w = __expf(gp[i] + gp[N_NODES + i] - m);
            acc += w * __bfloat162float(pfeat[(size_t)i * DIM + c]);
        }
        acc *= inv;
        atomicAdd(&out_acc[g * DIM + c], acc);
        return;
    }
    if ((int)blockIdx.x < poolBlocks + fillBlocks) {
        int e = (blockIdx.x - poolBlocks) * 256 + tid;
        if (e < N_EDGES) {
            int d = dst[e];
            int pos = rp[d] + atomicAdd(&cursor[d], 1);
            esrc[pos] = src[e];
        }
        return;
    }
    const int t = blockIdx.x - poolBlocks - fillBlocks;
    const int mbx = t % NODE_BLOCKS;
    const int head = t / NODE_BLOCKS;
    fc_block((const short*)A, (const short*)B, C, M, ans, and_, s_ns, s_nd,
             lsA, lsB, tid, mbx, head);
}

// ---------------- aggregate: one WAVE per dst node, two-phase (R20 win) -----
__global__ __launch_bounds__(256) void agg_kernel(
    const unsigned* __restrict__ h2, const int* __restrict__ rp,
    const int* __restrict__ esrc, const float* __restrict__ s_ns,
    const float* __restrict__ s_nd, bf16* __restrict__ agg)
{
    __shared__ float4 pv[4][64];
    const int wv = threadIdx.x >> 6;
    const int lane = threadIdx.x & 63;
    const int node = blockIdx.x * 4 + wv;
    if (node >= N_NODES) return;
    const int beg = rp[node], end = rp[node + 1];
    const int cnt = end - beg;
    unsigned* outp = (unsigned*)(agg + (size_t)node * (HEADS * DIM));
    if (cnt <= 0) {
        outp[lane] = 0u; outp[64 + lane] = 0u; outp[128 + lane] = 0u;
        return;
    }
    const float snd0 = s_nd[node * 3 + 0];
    const float snd1 = s_nd[node * 3 + 1];
    const float snd2 = s_nd[node * 3 + 2];
    float ss0 = 0.f, ss1 = 0.f, ss2 = 0.f;
    float a0 = 0.f, a1 = 0.f, a2 = 0.f, a3 = 0.f, a4 = 0.f, a5 = 0.f;
    for (int c0 = 0; c0 < cnt; c0 += 64) {
        const int ce = min(64, cnt - c0);
        if (lane < ce) {
            int s = esrc[beg + c0 + lane];
            float4 r;
            r.x = __expf(leaky(s_ns[s * 3 + 0] + snd0));
            r.y = __expf(leaky(s_ns[s * 3 + 1] + snd1));
            r.z = __expf(leaky(s_ns[s * 3 + 2] + snd2));
            r.w = __int_as_float(s);
            pv[wv][lane] = r;
        }
#pragma unroll 8
        for (int j = 0; j < ce; ++j) {
            float4 e = pv[wv][j];              // broadcast ds_read_b128
            int s = __float_as_int(e.w);
            ss0 += e.x; ss1 += e.y; ss2 += e.z;
            const unsigned* hp = h2 + (size_t)s * 192;
            unsigned w0 = hp[lane];
            unsigned w1 = hp[64 + lane];
            unsigned w2 = hp[128 + lane];
            a0 += e.x * lo2f(w0); a1 += e.x * hi2f(w0);
            a2 += e.y * lo2f(w1); a3 += e.y * hi2f(w1);
            a4 += e.z * lo2f(w2); a5 += e.z * hi2f(w2);
        }
    }
    float i0 = 1.f / ss0, i1 = 1.f / ss1, i2 = 1.f / ss2;
    outp[lane]       = packbf(a0 * i0, a1 * i0);
    outp[64 + lane]  = packbf(a2 * i1, a3 * i1);
    outp[128 + lane] = packbf(a4 * i2, a5 * i2);
}

// ---------------- standalone final pool (no fence — R20 errata) -------------
__global__ __launch_bounds__(256) void pool_acc(
    const bf16* __restrict__ feat, const float* __restrict__ gp,
    const int* __restrict__ gptr, float* __restrict__ out_acc)
{
    const int g = blockIdx.x;
    const int chunk = blockIdx.y;
    const int tid = threadIdx.x;
    const int beg = gptr[g], end = gptr[g + 1];
    if (beg >= end) return;
    __shared__ float red[4];
    float m = -1e30f;
    for (int i = beg + tid; i < end; i += 256)
        m = fmaxf(m, gp[i] + gp[N_NODES + i]);
#pragma unroll
    for (int o = 32; o > 0; o >>= 1) m = fmaxf(m, __shfl_xor(m, o));
    if ((tid & 63) == 0) red[tid >> 6] = m;
    __syncthreads();
    m = fmaxf(fmaxf(red[0], red[1]), fmaxf(red[2], red[3]));
    __syncthreads();
    float s = 0.f;
    for (int i = beg + tid; i < end; i += 256)
        s += __expf(gp[i] + gp[N_NODES + i] - m);
#pragma unroll
    for (int o = 32; o > 0; o >>= 1) s += __shfl_xor(s, o);
    if ((tid & 63) == 0) red[tid >> 6] = s;
    __syncthreads();
    float inv = 1.f / (red[0] + red[1] + red[2] + red[3]);
    const int p = tid >> 7;
    const int c = tid & 127;
    float acc = 0.f;
    for (int i = beg + chunk * 2 + p; i < end; i += 16) {
        float w = __expf(gp[i] + gp[N_NODES + i] - m);
        acc += w * __bfloat162float(feat[(size_t)i * DIM + c]);
    }
    acc *= inv;
    atomicAdd(&out_acc[g * DIM + c], acc);
}

__global__ void writeout_kernel(const float* __restrict__ out_acc,
                                void* __restrict__ out, const int* __restrict__ flag) {
    int i = blockIdx.x * 256 + threadIdx.x;
    if (i < NGRAPH * DIM) {
        float v = out_acc[i] * (1.f / 3.f);
        if ((*flag) > 8) ((float*)out)[i] = v;
        else ((bf16*)out)[i] = __float2bfloat16(v);
    }
}

// ---------------- host launcher ----------------
extern "C" void kernel_launch(void* const* d_in, const int* in_sizes, int n_in,
                              void* d_out, int out_size, void* d_ws, size_t ws_size,
                              hipStream_t stream)
{
    const void* feat_in = d_in[0];
    const int* src = (const int*)d_in[1];
    const int* dst = (const int*)d_in[2];
    const int* gid = (const int*)d_in[3];

    char* base = (char*)d_ws;
    size_t off = 0;
    auto carve = [&](size_t bytes) -> void* {
        void* p = base + off;
        off = (off + bytes + 255) & ~(size_t)255;
        return p;
    };
    int* dflag = (int*)carve(256);   // NOT zeroed; init block 0 stores it
    size_t zbytes = sizeof(int) * 2 * N_NODES + sizeof(float) * NGRAPH * DIM;
    char* zreg  = (char*)carve(zbytes);
    int* deg    = (int*)zreg;
    int* cursor = deg + N_NODES;
    float* out_acc = (float*)(cursor + N_NODES);
    float* gpart3 = (float*)carve(sizeof(float) * LAYERS * 2 * N_NODES);
    int* rp     = (int*)carve(sizeof(int) * (N_NODES + 1));
    int* gptr   = (int*)carve(sizeof(int) * (NGRAPH + 1));
    int* esrc   = (int*)carve(sizeof(int) * N_EDGES);
    float* s_ns = (float*)carve(sizeof(float) * N_NODES * HEADS);
    float* s_nd = (float*)carve(sizeof(float) * N_NODES * HEADS);
    bf16* featA = (bf16*)carve(sizeof(bf16) * N_NODES * DIM);
    bf16* featB = (bf16*)carve(sizeof(bf16) * N_NODES * DIM);
    bf16* cfc   = (bf16*)carve(sizeof(bf16) * LAYERS * HEADS * DIM * DIM);
    bf16* cans  = (bf16*)carve(sizeof(bf16) * LAYERS * HEADS * DIM);
    bf16* cand  = (bf16*)carve(sizeof(bf16) * LAYERS * HEADS * DIM);
    bf16* ctw   = (bf16*)carve(sizeof(bf16) * LAYERS * DIM * HEADS * DIM);
    bf16* ctb   = (bf16*)carve(sizeof(bf16) * LAYERS * DIM);
    bf16* cp1w  = (bf16*)carve(sizeof(bf16) * LAYERS * 2 * DIM * DIM);
    bf16* cp1b  = (bf16*)carve(sizeof(bf16) * LAYERS * 2 * DIM);
    bf16* cp2w  = (bf16*)carve(sizeof(bf16) * LAYERS * 2 * DIM);
    bf16* hbuf   = (bf16*)carve(sizeof(bf16) * N_NODES * HEADS * DIM);
    bf16* aggbuf = (bf16*)carve(sizeof(bf16) * N_NODES * HEADS * DIM);
    carve(131072);   // pad: GEMM A-tile tail overreads

    if (off > ws_size) {
        sentinel_kernel<<<(out_size + 255) / 256, 256, 0, stream>>>(
            (bf16*)d_out, out_size);
        return;
    }

    init_kernel<<<128, 256, 0, stream>>>(
        (unsigned*)zreg, (int)(zbytes / 4), (const unsigned short*)feat_in, dflag);

    CvtArgs ca;
    const int cvt_n[NCVT] = {
        N_NODES * DIM, LAYERS * HEADS * DIM * DIM, LAYERS * HEADS * DIM,
        LAYERS * HEADS * DIM, LAYERS * DIM * HEADS * DIM, LAYERS * DIM,
        LAYERS * 2 * DIM * DIM, LAYERS * 2 * DIM, LAYERS * 2 * DIM };
    bf16* cvt_dst[NCVT] = { featA, cfc, cans, cand, ctw, ctb, cp1w, cp1b, cp2w };
    const int cvt_src_idx[NCVT] = { 0, 4, 5, 6, 7, 8, 9, 10, 11 };
    int total4 = 0;
    for (int s = 0; s < NCVT; ++s) {
        ca.src[s] = d_in[cvt_src_idx[s]];
        ca.dst[s] = cvt_dst[s];
        ca.n[s] = cvt_n[s];
        ca.n4[s] = (cvt_n[s] + 3) / 4;
        total4 += ca.n4[s];
    }
    const int cvtBlocks = (total4 + 255) / 256;
    const int cntBlocks = (N_EDGES + 255) / 256;
    cvtcount_kernel<<<cvtBlocks + cntBlocks, 256, 0, stream>>>(
        ca, dflag, dst, deg, cvtBlocks);

    scan_gptr_kernel<<<1, 256, 0, stream>>>(deg, rp, gid, gptr);

    bf16* fin = featA;
    bf16* fout = featB;
    for (int d = 0; d < LAYERS; ++d) {
        float* gpart = gpart3 + (size_t)d * 2 * N_NODES;
        const int poolBlocks = (d == 0) ? 0 : NGRAPH * 8;
        const int fillBlocks = (d == 0) ? cntBlocks : 0;
        poolfc_kernel<<<poolBlocks + fillBlocks + NODE_BLOCKS * 3, 256, 0, stream>>>(
            fin, (d == 0) ? nullptr : gpart3 + (size_t)(d - 1) * 2 * N_NODES,
            gptr, out_acc,
            fin, cfc + (size_t)d * HEADS * DIM * DIM, hbuf, N_NODES,
            cans + (size_t)d * HEADS * DIM, cand + (size_t)d * HEADS * DIM,
            s_ns, s_nd, src, dst, rp, cursor, esrc, poolBlocks, fillBlocks);
        agg_kernel<<<(N_NODES + 3) / 4, 256, 0, stream>>>(
            (const unsigned*)hbuf, rp, esrc, s_ns, s_nd, aggbuf);
        gemm_mfma<0, 3><<<dim3(NODE_BLOCKS, 1), 256, 0, stream>>>(
            aggbuf, ctw + (size_t)d * DIM * HEADS * DIM, fout,
            N_NODES, DIM, ctb + (size_t)d * DIM, fin,
            (d < LAYERS - 1) ? 1 : 0, nullptr, nullptr);
        gemm_mfma<2, 1><<<dim3(NODE_BLOCKS, 2), 256, 0, stream>>>(
            fout, cp1w + (size_t)d * 2 * DIM * DIM, nullptr,
            N_NODES, 2 * DIM, cp1b + (size_t)d * 2 * DIM, nullptr, 1,
            cp2w + (size_t)d * 2 * DIM, gpart);
        bf16* t = fin; fin = fout; fout = t;
    }
    pool_acc<<<dim3(NGRAPH, 8), 256, 0, stream>>>(
        fin, gpart3 + (size_t)2 * 2 * N_NODES, gptr, out_acc);
    writeout_kernel<<<(NGRAPH * DIM + 255) / 256, 256, 0, stream>>>(
        out_acc, d_out, dflag);
}